// Round 10
// baseline (162.264 us; speedup 1.0000x reference)
//
#include <hip/hip_runtime.h>
#include <hip/hip_bf16.h>

#define N_NODES 50000
#define N_EDGES 600000
#define IN_F 256
#define OUT_F 128
#define GEMM_BLOCKS 196    // 256 rows per block
#define NBUCK 391          // buckets 0..390 = row >> 7 (128 rows each)
#define NBUCKA 392         // padded size for arrays
#define BROWS 128          // rows per bucket
#define NBLK_E 256         // scatter blocks (r9: 128->256, halves serial chains)
#define EPB 2344           // ceil(600000/256) edges per block
#define ITERS 5            // ceil(EPB/512)
#define CAP 2048           // slot capacity per bucket (mean 1534, sigma~39: 13 sigma)

typedef __bf16 bf16x8 __attribute__((ext_vector_type(8)));
typedef __bf16 bf16x2 __attribute__((ext_vector_type(2)));
typedef float  f32x4  __attribute__((ext_vector_type(4)));

__device__ __forceinline__ void async_copy16(void* lds, const void* g) {
    __builtin_amdgcn_global_load_lds(
        (const __attribute__((address_space(1))) void*)g,
        (__attribute__((address_space(3))) void*)lds, 16, 0, 0);
}

// ---------------------------------------------------------------------------
// Kernel 0: prep. Blocks 0..127: wt_sw = bf16 W^T pre-swizzled so a LINEAR
// 64KB LDS copy yields the XOR-swizzled layout the GEMM fragment reads expect:
//   LDS byte (n<<9) + (2k ^ ((n&7)<<4)) holds bf16(w[k][n]).
// Block 128: zero cursor[] (workspace is poisoned every iteration; runs inside
// the captured graph so every replay is idempotent).
// NOTE (r9): cooperative mega-kernel is NOT an option — hipLaunchCooperative-
// Kernel is not graph-capturable in this harness (r9: silent no-op, out=0).
// ---------------------------------------------------------------------------
__global__ __launch_bounds__(256) void gcn_prep(const float* __restrict__ w,
                                                __bf16* __restrict__ wt_sw,
                                                int* __restrict__ cursor) {
    if (blockIdx.x == 128) {
        for (int j = threadIdx.x; j < NBUCKA; j += 256) cursor[j] = 0;
        return;
    }
    int i = blockIdx.x * 256 + threadIdx.x;       // 0..32767
    int n = i >> 8;                               // 0..127 (output col)
    int k = (i & 255) ^ ((n & 7) << 3);           // 0..255 (input feature)
    wt_sw[i] = (__bf16)w[k * OUT_F + n];
}

// x-load pipeline macros: 3-buffer rotation, prefetch distance 2.
// (r4 lesson: use underscore-suffixed names so ## pastes identifier+identifier.)
#define GLOAD(P, ks)                                    \
    P##_0 = *(const float4*)(xp0 + (ks) * 32);          \
    P##_1 = *(const float4*)(xp0 + (ks) * 32 + 4);      \
    P##_2 = *(const float4*)(xp1 + (ks) * 32);          \
    P##_3 = *(const float4*)(xp1 + (ks) * 32 + 4);

#define KSTEP(P, ks) {                                                             \
    bf16x8 af0 = { (__bf16)P##_0.x, (__bf16)P##_0.y, (__bf16)P##_0.z, (__bf16)P##_0.w, \
                   (__bf16)P##_1.x, (__bf16)P##_1.y, (__bf16)P##_1.z, (__bf16)P##_1.w };\
    bf16x8 af1 = { (__bf16)P##_2.x, (__bf16)P##_2.y, (__bf16)P##_2.z, (__bf16)P##_2.w, \
                   (__bf16)P##_3.x, (__bf16)P##_3.y, (__bf16)P##_3.z, (__bf16)P##_3.w };\
    _Pragma("unroll")                                                              \
    for (int nt = 0; nt < 8; nt++) {                                               \
        int nrow = nt * 16 + m;                                                    \
        const bf16x8 bf = *(const bf16x8*)(smem + (nrow << 9) +                    \
                            (((ks) * 64 + quad * 16) ^ ((nrow & 7) << 4)));        \
        acc0[nt] = __builtin_amdgcn_mfma_f32_16x16x32_bf16(af0, bf, acc0[nt], 0, 0, 0); \
        acc1[nt] = __builtin_amdgcn_mfma_f32_16x16x32_bf16(af1, bf, acc1[nt], 0, 0, 0); \
    } }

// ---------------------------------------------------------------------------
// Kernel 1 (fused): blocks [0,196) = GEMM  support = bf16(x @ W);
//                   blocks [196,452) = scatter to fixed-capacity buckets.
// Scatter: bucket g owns slots [g*CAP, g*CAP+CAP) so NO exclusive scan exists
// anywhere. Per block: (a) one pass over its ~2344 edges -> rows cached in
// regs + LDS histogram; (b) ONE global atomicAdd per (block,bucket) reserves
// a contiguous slice (~100K atomics total); (c) per-edge LDS-atomic ranks ->
// scatter. Latency hides under the co-scheduled GEMM blocks.
// ---------------------------------------------------------------------------
__global__ __launch_bounds__(512, 3) void gcn_gemm_scatter(const float* __restrict__ x,
                                                           const __bf16* __restrict__ wt_sw,
                                                           __bf16* __restrict__ support,
                                                           const int* __restrict__ erows,
                                                           const int* __restrict__ ecols,
                                                           const float* __restrict__ evals,
                                                           int* __restrict__ cursor,
                                                           int2* __restrict__ bucketed) {
    __shared__ char smem[65536];   // GEMM: W^T then C-tile; scatter: lh[392]
    const int t = threadIdx.x;

    if (blockIdx.x >= GEMM_BLOCKS) {
        // ---------------- scatter part ----------------
        int b = blockIdx.x - GEMM_BLOCKS;         // 0..255
        int* lh = (int*)smem;                     // [NBUCKA] counts -> bases
        for (int j = t; j < NBUCKA; j += 512) lh[j] = 0;
        __syncthreads();
        int e0 = b * EPB;
        int e1 = e0 + EPB; if (e1 > N_EDGES) e1 = N_EDGES;
        int myr[ITERS];
#pragma unroll
        for (int j = 0; j < ITERS; j++) {         // static idx via unroll (rule #20)
            int e = e0 + j * 512 + t;
            myr[j] = -1;
            if (e < e1) {
                int r = erows[e];
                myr[j] = r;
                atomicAdd(&lh[r >> 7], 1);        // LDS atomic
            }
        }
        __syncthreads();
        if (t < NBUCKA) {                         // reserve contiguous slice
            int c = lh[t];
            lh[t] = c ? atomicAdd(&cursor[t], c) : 0;   // global atomic, 1/bucket
        }
        __syncthreads();
#pragma unroll
        for (int j = 0; j < ITERS; j++) {
            int r = myr[j];
            if (r >= 0) {
                int e = e0 + j * 512 + t;
                int g = r >> 7;
                int rank = atomicAdd(&lh[g], 1);  // LDS atomic return
                if (rank < CAP)                   // 13-sigma guard
                    bucketed[((size_t)g << 11) + rank] =
                        make_int2(((r & 127) << 16) | ecols[e],
                                  __float_as_int(evals[e]));
            }
        }
        return;
    }

    // ---------------- GEMM part ----------------
    const int wave = t >> 6;                         // 0..7
    const int lane = t & 63;
    const int m    = lane & 15;
    const int quad = lane >> 4;

    // stage 64KB W^T: linear LDS dest, 8 iters x (8 waves x 64 lanes x 16B)
    {
        const char* gW = (const char*)wt_sw + wave * 1024 + lane * 16;
        char* lW = smem + wave * 1024;               // wave-uniform base
#pragma unroll
        for (int it = 0; it < 8; it++)
            async_copy16(lW + it * 8192, gW + it * 8192);
    }
    __syncthreads();   // drains vmcnt(0) for the global_load_lds queue

    const int row0 = blockIdx.x * 256 + wave * 32;
    int r0 = row0 + m;
    int r1 = row0 + 16 + m;
    const float* xp0 = x + (size_t)(r0 < N_NODES ? r0 : 0) * IN_F + quad * 8;
    const float* xp1 = x + (size_t)(r1 < N_NODES ? r1 : 0) * IN_F + quad * 8;

    f32x4 acc0[8], acc1[8];
#pragma unroll
    for (int nt = 0; nt < 8; nt++) {
        acc0[nt] = (f32x4){0.f, 0.f, 0.f, 0.f};
        acc1[nt] = (f32x4){0.f, 0.f, 0.f, 0.f};
    }

    float4 A_0, A_1, A_2, A_3, B_0, B_1, B_2, B_3, C_0, C_1, C_2, C_3;
    GLOAD(A, 0) GLOAD(B, 1)
    GLOAD(C, 2) KSTEP(A, 0)
    GLOAD(A, 3) KSTEP(B, 1)
    GLOAD(B, 4) KSTEP(C, 2)
    GLOAD(C, 5) KSTEP(A, 3)
    GLOAD(A, 6) KSTEP(B, 4)
    GLOAD(B, 7) KSTEP(C, 5)
    KSTEP(A, 6)
    KSTEP(B, 7)

    // ---- epilogue: transpose through LDS, then full-line vector stores ----
    __syncthreads();   // all waves done reading W from smem
#pragma unroll
    for (int nt = 0; nt < 8; nt++) {
        int cb = (nt * 16 + m) * 2;                  // col byte offset
#pragma unroll
        for (int r = 0; r < 4; r++) {
            int lr0 = wave * 32 + quad * 4 + r;      // C/D layout [m89]: row=quad*4+r
            int lr1 = lr0 + 16;
            *(__bf16*)(smem + (lr0 << 8) + (cb ^ ((lr0 & 7) << 4))) = (__bf16)acc0[nt][r];
            *(__bf16*)(smem + (lr1 << 8) + (cb ^ ((lr1 & 7) << 4))) = (__bf16)acc1[nt][r];
        }
    }
    __syncthreads();
    {
        int row  = t >> 1;                           // 0..255
        int half = t & 1;
        int g = blockIdx.x * 256 + row;
        if (g < N_NODES) {
            char* dst = (char*)(support + (size_t)g * OUT_F) + half * 128;
#pragma unroll
            for (int j = 0; j < 8; j++) {
                int boff = (half * 128 + j * 16) ^ ((row & 7) << 4);
                *(bf16x8*)(dst + j * 16) = *(const bf16x8*)(smem + (row << 8) + boff);
            }
        }
    }
}

// ---------------------------------------------------------------------------
// Kernel 2 (fused rank+aggregate, r9 rework): one block per 128-row bucket.
// vs r8: bucketed is read from global ONCE (histogramming during the LDS
// load), the rank-scatter is LDS->LDS, and total LDS drops 64KB -> ~36KB so
// FOUR blocks/CU fit (launch_bounds(512,8) pins VGPR<=64) — doubling the wave
// pool that hides the per-edge 256B support-gather latency.
//  (a) load slice -> se_raw + histogram(128 bins) -> scan -> LDS rank scatter
//      into se (row-sorted, col|val);
//  (b) aggregate: wave wv owns 16 rows; per row all 64 lanes gather
//      support[col] (256B coalesced), unroll-4 MLP, rows independent.
// ---------------------------------------------------------------------------
__global__ __launch_bounds__(512, 8) void gcn_agg_sorted(const __bf16* __restrict__ support,
                                                         const int2* __restrict__ bucketed,
                                                         const int* __restrict__ cursor,
                                                         const float* __restrict__ bias,
                                                         float* __restrict__ out) {
    __shared__ int2 se_raw[CAP];      // 16 KB unsorted edges (one global pass)
    __shared__ int2 se[CAP];          // 16 KB row-sorted edges (col, val)
    __shared__ int  lh[BROWS];        // per-row counts
    __shared__ int  rs[BROWS];        // per-row exclusive start
    __shared__ int  run[BROWS];       // running cursor for rank scatter
    __shared__ int  sc[512];          // scan buffer
    const int g  = blockIdx.x;
    const int t  = threadIdx.x;
    const int wv = t >> 6, ln = t & 63;

    const int beg = g << 11;                      // g * CAP
    int ne = cursor[g]; if (ne > CAP) ne = CAP; if (ne < 0) ne = 0;

    if (t < BROWS) lh[t] = 0;
    __syncthreads();
    for (int i = t; i < ne; i += 512) {           // single global pass
        int2 cv = bucketed[beg + i];
        se_raw[i] = cv;
        atomicAdd(&lh[cv.x >> 16], 1);
    }
    __syncthreads();

    int v = (t < BROWS) ? lh[t] : 0;
    sc[t] = v;
    __syncthreads();
#pragma unroll
    for (int off = 1; off < BROWS; off <<= 1) {
        int x = (t >= off) ? sc[t - off] : 0;
        __syncthreads();
        sc[t] += x;
        __syncthreads();
    }
    if (t < BROWS) { rs[t] = sc[t] - v; run[t] = sc[t] - v; }
    __syncthreads();

    for (int i = t; i < ne; i += 512) {           // LDS -> LDS rank scatter
        int2 cv = se_raw[i];
        int p = atomicAdd(&run[cv.x >> 16], 1);   // p < ne <= CAP by construction
        se[p] = make_int2(cv.x & 0xFFFF, cv.y);
    }
    __syncthreads();

    // aggregate: wave wv owns rows [wv*16, wv*16+16)
    const int grow0 = g * BROWS;
    const __bf16* spL = support + ln * 2;
    const float2 bias2 = *(const float2*)&bias[ln * 2];
    for (int rr = 0; rr < 16; rr++) {
        int row  = wv * 16 + rr;
        int grow = grow0 + row;
        if (grow >= N_NODES) break;               // wave-uniform
        float2 acc = bias2;
        int b0 = rs[row];
        int b1 = b0 + lh[row];
        int j = b0;
        for (; j + 3 < b1; j += 4) {
            int2 e0 = se[j];
            int2 e1 = se[j + 1];
            int2 e2 = se[j + 2];
            int2 e3 = se[j + 3];
            bf16x2 s0 = *(const bf16x2*)(spL + (size_t)e0.x * OUT_F);
            bf16x2 s1 = *(const bf16x2*)(spL + (size_t)e1.x * OUT_F);
            bf16x2 s2 = *(const bf16x2*)(spL + (size_t)e2.x * OUT_F);
            bf16x2 s3 = *(const bf16x2*)(spL + (size_t)e3.x * OUT_F);
            float v0 = __int_as_float(e0.y);
            float v1 = __int_as_float(e1.y);
            float v2 = __int_as_float(e2.y);
            float v3 = __int_as_float(e3.y);
            acc.x += v0 * (float)s0.x + v1 * (float)s1.x;
            acc.y += v0 * (float)s0.y + v1 * (float)s1.y;
            acc.x += v2 * (float)s2.x + v3 * (float)s3.x;
            acc.y += v2 * (float)s2.y + v3 * (float)s3.y;
        }
        for (; j < b1; j++) {
            int2 e0 = se[j];
            bf16x2 s0 = *(const bf16x2*)(spL + (size_t)e0.x * OUT_F);
            float v0 = __int_as_float(e0.y);
            acc.x += v0 * (float)s0.x;
            acc.y += v0 * (float)s0.y;
        }
        *(float2*)&out[(size_t)grow * OUT_F + ln * 2] = acc;
    }
}

// ---------------------------------------------------------------------------
static inline size_t align_up(size_t v, size_t a) { return (v + a - 1) & ~(a - 1); }

extern "C" void kernel_launch(void* const* d_in, const int* in_sizes, int n_in,
                              void* d_out, int out_size, void* d_ws, size_t ws_size,
                              hipStream_t stream) {
    const float* x     = (const float*)d_in[0];   // [50000, 256]
    const int*   erows = (const int*)d_in[1];     // [600000]
    const int*   ecols = (const int*)d_in[2];     // [600000]
    const float* evals = (const float*)d_in[3];   // [600000]
    const float* w     = (const float*)d_in[4];   // [256, 128]
    const float* bias  = (const float*)d_in[5];   // [128]
    float* out = (float*)d_out;                   // [50000, 128]

    // workspace layout (all regions 64B-aligned; ~19.3 MB total)
    size_t off = 0;
    __bf16* support   = (__bf16*)((char*)d_ws + off);
    off = align_up(off + (size_t)N_NODES * OUT_F * 2, 64);
    __bf16* wt_sw     = (__bf16*)((char*)d_ws + off);
    off = align_up(off + (size_t)IN_F * OUT_F * 2, 64);
    int*    cursor    = (int*)((char*)d_ws + off);        // [392]
    off = align_up(off + (size_t)NBUCKA * 4, 64);
    int2*   bucketed  = (int2*)((char*)d_ws + off);       // [391][2048]

    // 0) build swizzled bf16 W^T + zero cursor
    gcn_prep<<<129, 256, 0, stream>>>(w, wt_sw, cursor);

    // 1) fused GEMM + fixed-capacity bucket scatter
    gcn_gemm_scatter<<<GEMM_BLOCKS + NBLK_E, 512, 0, stream>>>(
        x, wt_sw, support, erows, ecols, evals, cursor, bucketed);

    // 2) fused in-LDS rank + per-row-wave aggregate + bias
    gcn_agg_sorted<<<NBUCK, 512, 0, stream>>>(support, bucketed, cursor, bias, out);
}

// Round 11
// 149.199 us; speedup vs baseline: 1.0876x; 1.0876x over previous
//
#include <hip/hip_runtime.h>
#include <hip/hip_bf16.h>

#define N_NODES 50000
#define N_EDGES 600000
#define IN_F 256
#define OUT_F 128
#define GEMM_BLOCKS 196    // 256 rows per block
#define NBUCK 782          // buckets 0..781 = row >> 6 (64 rows each)
#define NBUCKA 784         // padded size for arrays
#define BROWS 64           // rows per bucket
#define NBLK_E 256         // scatter blocks
#define EPB 2344           // ceil(600000/256) edges per block
#define ITERS 5            // ceil(EPB/512)
#define CAP 1024           // slot capacity per bucket (mean 768, sigma~28: 9 sigma)

typedef __bf16 bf16x8 __attribute__((ext_vector_type(8)));
typedef __bf16 bf16x2 __attribute__((ext_vector_type(2)));
typedef float  f32x4  __attribute__((ext_vector_type(4)));

__device__ __forceinline__ void async_copy16(void* lds, const void* g) {
    __builtin_amdgcn_global_load_lds(
        (const __attribute__((address_space(1))) void*)g,
        (__attribute__((address_space(3))) void*)lds, 16, 0, 0);
}

// ---------------------------------------------------------------------------
// Kernel 0: prep. Blocks 0..127: wt_sw = bf16 W^T pre-swizzled so a LINEAR
// 64KB LDS copy yields the XOR-swizzled layout the GEMM fragment reads expect:
//   LDS byte (n<<9) + (2k ^ ((n&7)<<4)) holds bf16(w[k][n]).
// Block 128: zero cursor[] (workspace is poisoned every iteration; runs inside
// the captured graph so every replay is idempotent).
// NOTE (r9): hipLaunchCooperativeKernel is NOT graph-capturable here (silent
// no-op, out=0) — multi-kernel pipeline is mandatory.
// ---------------------------------------------------------------------------
__global__ __launch_bounds__(256) void gcn_prep(const float* __restrict__ w,
                                                __bf16* __restrict__ wt_sw,
                                                int* __restrict__ cursor) {
    if (blockIdx.x == 128) {
        for (int j = threadIdx.x; j < NBUCKA; j += 256) cursor[j] = 0;
        return;
    }
    int i = blockIdx.x * 256 + threadIdx.x;       // 0..32767
    int n = i >> 8;                               // 0..127 (output col)
    int k = (i & 255) ^ ((n & 7) << 3);           // 0..255 (input feature)
    wt_sw[i] = (__bf16)w[k * OUT_F + n];
}

// x-load pipeline macros: 3-buffer rotation, prefetch distance 2.
// (r4 lesson: use underscore-suffixed names so ## pastes identifier+identifier.)
#define GLOAD(P, ks)                                    \
    P##_0 = *(const float4*)(xp0 + (ks) * 32);          \
    P##_1 = *(const float4*)(xp0 + (ks) * 32 + 4);      \
    P##_2 = *(const float4*)(xp1 + (ks) * 32);          \
    P##_3 = *(const float4*)(xp1 + (ks) * 32 + 4);

#define KSTEP(P, ks) {                                                             \
    bf16x8 af0 = { (__bf16)P##_0.x, (__bf16)P##_0.y, (__bf16)P##_0.z, (__bf16)P##_0.w, \
                   (__bf16)P##_1.x, (__bf16)P##_1.y, (__bf16)P##_1.z, (__bf16)P##_1.w };\
    bf16x8 af1 = { (__bf16)P##_2.x, (__bf16)P##_2.y, (__bf16)P##_2.z, (__bf16)P##_2.w, \
                   (__bf16)P##_3.x, (__bf16)P##_3.y, (__bf16)P##_3.z, (__bf16)P##_3.w };\
    _Pragma("unroll")                                                              \
    for (int nt = 0; nt < 8; nt++) {                                               \
        int nrow = nt * 16 + m;                                                    \
        const bf16x8 bf = *(const bf16x8*)(smem + (nrow << 9) +                    \
                            (((ks) * 64 + quad * 16) ^ ((nrow & 7) << 4)));        \
        acc0[nt] = __builtin_amdgcn_mfma_f32_16x16x32_bf16(af0, bf, acc0[nt], 0, 0, 0); \
        acc1[nt] = __builtin_amdgcn_mfma_f32_16x16x32_bf16(af1, bf, acc1[nt], 0, 0, 0); \
    } }

// ---------------------------------------------------------------------------
// Kernel 1 (fused): blocks [0,196) = GEMM  support = bf16(x @ W);
//                   blocks [196,452) = scatter to fixed-capacity buckets.
// Scatter: bucket g owns slots [g*CAP, g*CAP+CAP) so NO exclusive scan exists
// anywhere. Per block: (a) one pass over its ~2344 edges -> rows cached in
// regs + LDS histogram (784 bins); (b) ONE global atomicAdd per (block,
// bucket) reserves a contiguous slice; (c) per-edge LDS-atomic ranks ->
// scatter. Latency hides under the co-scheduled GEMM blocks.
// ---------------------------------------------------------------------------
__global__ __launch_bounds__(512, 3) void gcn_gemm_scatter(const float* __restrict__ x,
                                                           const __bf16* __restrict__ wt_sw,
                                                           __bf16* __restrict__ support,
                                                           const int* __restrict__ erows,
                                                           const int* __restrict__ ecols,
                                                           const float* __restrict__ evals,
                                                           int* __restrict__ cursor,
                                                           int2* __restrict__ bucketed) {
    __shared__ char smem[65536];   // GEMM: W^T then C-tile; scatter: lh[784]
    const int t = threadIdx.x;

    if (blockIdx.x >= GEMM_BLOCKS) {
        // ---------------- scatter part ----------------
        int b = blockIdx.x - GEMM_BLOCKS;         // 0..255
        int* lh = (int*)smem;                     // [NBUCKA] counts -> bases
        for (int j = t; j < NBUCKA; j += 512) lh[j] = 0;
        __syncthreads();
        int e0 = b * EPB;
        int e1 = e0 + EPB; if (e1 > N_EDGES) e1 = N_EDGES;
        int myr[ITERS];
#pragma unroll
        for (int j = 0; j < ITERS; j++) {         // static idx via unroll (rule #20)
            int e = e0 + j * 512 + t;
            myr[j] = -1;
            if (e < e1) {
                int r = erows[e];
                myr[j] = r;
                atomicAdd(&lh[r >> 6], 1);        // LDS atomic
            }
        }
        __syncthreads();
        for (int j0 = t; j0 < NBUCKA; j0 += 512) {  // reserve contiguous slices
            int c = lh[j0];
            lh[j0] = c ? atomicAdd(&cursor[j0], c) : 0;   // global atomic, 1/bucket
        }
        __syncthreads();
#pragma unroll
        for (int j = 0; j < ITERS; j++) {
            int r = myr[j];
            if (r >= 0) {
                int e = e0 + j * 512 + t;
                int g = r >> 6;
                int rank = atomicAdd(&lh[g], 1);  // LDS atomic return
                if (rank < CAP)                   // 9-sigma guard
                    bucketed[((size_t)g << 10) + rank] =
                        make_int2(((r & 63) << 16) | ecols[e],
                                  __float_as_int(evals[e]));
            }
        }
        return;
    }

    // ---------------- GEMM part ----------------
    const int wave = t >> 6;                         // 0..7
    const int lane = t & 63;
    const int m    = lane & 15;
    const int quad = lane >> 4;

    // stage 64KB W^T: linear LDS dest, 8 iters x (8 waves x 64 lanes x 16B)
    {
        const char* gW = (const char*)wt_sw + wave * 1024 + lane * 16;
        char* lW = smem + wave * 1024;               // wave-uniform base
#pragma unroll
        for (int it = 0; it < 8; it++)
            async_copy16(lW + it * 8192, gW + it * 8192);
    }
    __syncthreads();   // drains vmcnt(0) for the global_load_lds queue

    const int row0 = blockIdx.x * 256 + wave * 32;
    int r0 = row0 + m;
    int r1 = row0 + 16 + m;
    const float* xp0 = x + (size_t)(r0 < N_NODES ? r0 : 0) * IN_F + quad * 8;
    const float* xp1 = x + (size_t)(r1 < N_NODES ? r1 : 0) * IN_F + quad * 8;

    f32x4 acc0[8], acc1[8];
#pragma unroll
    for (int nt = 0; nt < 8; nt++) {
        acc0[nt] = (f32x4){0.f, 0.f, 0.f, 0.f};
        acc1[nt] = (f32x4){0.f, 0.f, 0.f, 0.f};
    }

    float4 A_0, A_1, A_2, A_3, B_0, B_1, B_2, B_3, C_0, C_1, C_2, C_3;
    GLOAD(A, 0) GLOAD(B, 1)
    GLOAD(C, 2) KSTEP(A, 0)
    GLOAD(A, 3) KSTEP(B, 1)
    GLOAD(B, 4) KSTEP(C, 2)
    GLOAD(C, 5) KSTEP(A, 3)
    GLOAD(A, 6) KSTEP(B, 4)
    GLOAD(B, 7) KSTEP(C, 5)
    KSTEP(A, 6)
    KSTEP(B, 7)

    // ---- epilogue: transpose through LDS, then full-line vector stores ----
    __syncthreads();   // all waves done reading W from smem
#pragma unroll
    for (int nt = 0; nt < 8; nt++) {
        int cb = (nt * 16 + m) * 2;                  // col byte offset
#pragma unroll
        for (int r = 0; r < 4; r++) {
            int lr0 = wave * 32 + quad * 4 + r;      // C/D layout [m89]: row=quad*4+r
            int lr1 = lr0 + 16;
            *(__bf16*)(smem + (lr0 << 8) + (cb ^ ((lr0 & 7) << 4))) = (__bf16)acc0[nt][r];
            *(__bf16*)(smem + (lr1 << 8) + (cb ^ ((lr1 & 7) << 4))) = (__bf16)acc1[nt][r];
        }
    }
    __syncthreads();
    {
        int row  = t >> 1;                           // 0..255
        int half = t & 1;
        int g = blockIdx.x * 256 + row;
        if (g < N_NODES) {
            char* dst = (char*)(support + (size_t)g * OUT_F) + half * 128;
#pragma unroll
            for (int j = 0; j < 8; j++) {
                int boff = (half * 128 + j * 16) ^ ((row & 7) << 4);
                *(bf16x8*)(dst + j * 16) = *(const bf16x8*)(smem + (row << 8) + boff);
            }
        }
    }
}

// ---------------------------------------------------------------------------
// Kernel 2 (fused rank+aggregate, r10 rework): one block per 64-row bucket.
// r10 post-mortem: 391 blocks was GRID-limited (3128 waves / 256 CU ~ 12/CU,
// Occupancy 24.7%) — halving the bucket doubles blocks to 782 (~24 waves/CU)
// and halves each wave's serial row tail. LDS ~19KB.
//  (a) load slice -> se_raw + histogram(64 bins) -> scan -> LDS rank scatter
//      into se (row-sorted, col|val);
//  (b) aggregate: wave wv owns 8 rows; per row all 64 lanes gather
//      support[col] (256B coalesced), unroll-8 MLP, rows independent.
// ---------------------------------------------------------------------------
__global__ __launch_bounds__(512, 8) void gcn_agg_sorted(const __bf16* __restrict__ support,
                                                         const int2* __restrict__ bucketed,
                                                         const int* __restrict__ cursor,
                                                         const float* __restrict__ bias,
                                                         float* __restrict__ out) {
    __shared__ int2 se_raw[CAP];      // 8 KB unsorted edges (one global pass)
    __shared__ int2 se[CAP];          // 8 KB row-sorted edges (col, val)
    __shared__ int  lh[BROWS];        // per-row counts
    __shared__ int  rs[BROWS];        // per-row exclusive start
    __shared__ int  run[BROWS];       // running cursor for rank scatter
    __shared__ int  sc[128];          // scan buffer
    const int g  = blockIdx.x;
    const int t  = threadIdx.x;
    const int wv = t >> 6, ln = t & 63;

    const int beg = g << 10;                      // g * CAP
    int ne = cursor[g]; if (ne > CAP) ne = CAP; if (ne < 0) ne = 0;

    if (t < BROWS) lh[t] = 0;
    __syncthreads();
    for (int i = t; i < ne; i += 512) {           // single global pass
        int2 cv = bucketed[beg + i];
        se_raw[i] = cv;
        atomicAdd(&lh[cv.x >> 16], 1);
    }
    __syncthreads();

    if (t < 128) {
        int v = (t < BROWS) ? lh[t] : 0;
        sc[t] = v;
    }
    __syncthreads();
#pragma unroll
    for (int off = 1; off < BROWS; off <<= 1) {
        int x = 0;
        if (t < 128 && t >= off) x = sc[t - off];
        __syncthreads();
        if (t < 128) sc[t] += x;
        __syncthreads();
    }
    if (t < BROWS) {
        int v = lh[t];
        rs[t] = sc[t] - v;
        run[t] = sc[t] - v;
    }
    __syncthreads();

    for (int i = t; i < ne; i += 512) {           // LDS -> LDS rank scatter
        int2 cv = se_raw[i];
        int p = atomicAdd(&run[cv.x >> 16], 1);   // p < ne <= CAP by construction
        se[p] = make_int2(cv.x & 0xFFFF, cv.y);
    }
    __syncthreads();

    // aggregate: wave wv owns rows [wv*8, wv*8+8)
    const int grow0 = g * BROWS;
    const __bf16* spL = support + ln * 2;
    const float2 bias2 = *(const float2*)&bias[ln * 2];
    for (int rr = 0; rr < 8; rr++) {
        int row  = wv * 8 + rr;
        int grow = grow0 + row;
        if (grow >= N_NODES) break;               // wave-uniform
        float2 acc = bias2;
        float2 accB = make_float2(0.f, 0.f);
        int b0 = rs[row];
        int b1 = b0 + lh[row];
        int j = b0;
        for (; j + 7 < b1; j += 8) {              // unroll-8: 8 gathers in flight
            int2 e0 = se[j];
            int2 e1 = se[j + 1];
            int2 e2 = se[j + 2];
            int2 e3 = se[j + 3];
            int2 e4 = se[j + 4];
            int2 e5 = se[j + 5];
            int2 e6 = se[j + 6];
            int2 e7 = se[j + 7];
            bf16x2 s0 = *(const bf16x2*)(spL + (size_t)e0.x * OUT_F);
            bf16x2 s1 = *(const bf16x2*)(spL + (size_t)e1.x * OUT_F);
            bf16x2 s2 = *(const bf16x2*)(spL + (size_t)e2.x * OUT_F);
            bf16x2 s3 = *(const bf16x2*)(spL + (size_t)e3.x * OUT_F);
            bf16x2 s4 = *(const bf16x2*)(spL + (size_t)e4.x * OUT_F);
            bf16x2 s5 = *(const bf16x2*)(spL + (size_t)e5.x * OUT_F);
            bf16x2 s6 = *(const bf16x2*)(spL + (size_t)e6.x * OUT_F);
            bf16x2 s7 = *(const bf16x2*)(spL + (size_t)e7.x * OUT_F);
            float v0 = __int_as_float(e0.y);
            float v1 = __int_as_float(e1.y);
            float v2 = __int_as_float(e2.y);
            float v3 = __int_as_float(e3.y);
            float v4 = __int_as_float(e4.y);
            float v5 = __int_as_float(e5.y);
            float v6 = __int_as_float(e6.y);
            float v7 = __int_as_float(e7.y);
            acc.x  += v0 * (float)s0.x + v1 * (float)s1.x;
            acc.y  += v0 * (float)s0.y + v1 * (float)s1.y;
            accB.x += v2 * (float)s2.x + v3 * (float)s3.x;
            accB.y += v2 * (float)s2.y + v3 * (float)s3.y;
            acc.x  += v4 * (float)s4.x + v5 * (float)s5.x;
            acc.y  += v4 * (float)s4.y + v5 * (float)s5.y;
            accB.x += v6 * (float)s6.x + v7 * (float)s7.x;
            accB.y += v6 * (float)s6.y + v7 * (float)s7.y;
        }
        for (; j + 3 < b1; j += 4) {
            int2 e0 = se[j];
            int2 e1 = se[j + 1];
            int2 e2 = se[j + 2];
            int2 e3 = se[j + 3];
            bf16x2 s0 = *(const bf16x2*)(spL + (size_t)e0.x * OUT_F);
            bf16x2 s1 = *(const bf16x2*)(spL + (size_t)e1.x * OUT_F);
            bf16x2 s2 = *(const bf16x2*)(spL + (size_t)e2.x * OUT_F);
            bf16x2 s3 = *(const bf16x2*)(spL + (size_t)e3.x * OUT_F);
            float v0 = __int_as_float(e0.y);
            float v1 = __int_as_float(e1.y);
            float v2 = __int_as_float(e2.y);
            float v3 = __int_as_float(e3.y);
            acc.x  += v0 * (float)s0.x + v1 * (float)s1.x;
            acc.y  += v0 * (float)s0.y + v1 * (float)s1.y;
            accB.x += v2 * (float)s2.x + v3 * (float)s3.x;
            accB.y += v2 * (float)s2.y + v3 * (float)s3.y;
        }
        for (; j < b1; j++) {
            int2 e0 = se[j];
            bf16x2 s0 = *(const bf16x2*)(spL + (size_t)e0.x * OUT_F);
            float v0 = __int_as_float(e0.y);
            acc.x += v0 * (float)s0.x;
            acc.y += v0 * (float)s0.y;
        }
        acc.x += accB.x;
        acc.y += accB.y;
        *(float2*)&out[(size_t)grow * OUT_F + ln * 2] = acc;
    }
}

// ---------------------------------------------------------------------------
static inline size_t align_up(size_t v, size_t a) { return (v + a - 1) & ~(a - 1); }

extern "C" void kernel_launch(void* const* d_in, const int* in_sizes, int n_in,
                              void* d_out, int out_size, void* d_ws, size_t ws_size,
                              hipStream_t stream) {
    const float* x     = (const float*)d_in[0];   // [50000, 256]
    const int*   erows = (const int*)d_in[1];     // [600000]
    const int*   ecols = (const int*)d_in[2];     // [600000]
    const float* evals = (const float*)d_in[3];   // [600000]
    const float* w     = (const float*)d_in[4];   // [256, 128]
    const float* bias  = (const float*)d_in[5];   // [128]
    float* out = (float*)d_out;                   // [50000, 128]

    // workspace layout (all regions 64B-aligned; ~19.6 MB total)
    size_t off = 0;
    __bf16* support   = (__bf16*)((char*)d_ws + off);
    off = align_up(off + (size_t)N_NODES * OUT_F * 2, 64);
    __bf16* wt_sw     = (__bf16*)((char*)d_ws + off);
    off = align_up(off + (size_t)IN_F * OUT_F * 2, 64);
    int*    cursor    = (int*)((char*)d_ws + off);        // [784]
    off = align_up(off + (size_t)NBUCKA * 4, 64);
    int2*   bucketed  = (int2*)((char*)d_ws + off);       // [782][1024]

    // 0) build swizzled bf16 W^T + zero cursor
    gcn_prep<<<129, 256, 0, stream>>>(w, wt_sw, cursor);

    // 1) fused GEMM + fixed-capacity bucket scatter
    gcn_gemm_scatter<<<GEMM_BLOCKS + NBLK_E, 512, 0, stream>>>(
        x, wt_sw, support, erows, ecols, evals, cursor, bucketed);

    // 2) fused in-LDS rank + per-row-wave aggregate + bias
    gcn_agg_sorted<<<NBUCK, 512, 0, stream>>>(support, bucketed, cursor, bias, out);
}

// Round 12
// 140.512 us; speedup vs baseline: 1.1548x; 1.0618x over previous
//
#include <hip/hip_runtime.h>
#include <hip/hip_bf16.h>

#define N_NODES 50000
#define N_EDGES 600000
#define IN_F 256
#define OUT_F 128
#define GEMM_BLOCKS 196    // 256 rows per block
#define NBUCK 782          // buckets 0..781 = row >> 6 (64 rows each)
#define NBUCKA 784         // padded size for arrays
#define BROWS 64           // rows per bucket
#define NBLK_E 256         // scatter blocks
#define EPB 2344           // ceil(600000/256) edges per block
#define ITERS 5            // ceil(EPB/512)
#define CAP 1024           // slot capacity per bucket (mean 768, sigma~28: 9 sigma)

typedef __bf16 bf16x8 __attribute__((ext_vector_type(8)));
typedef __bf16 bf16x4 __attribute__((ext_vector_type(4)));
typedef __bf16 bf16x2 __attribute__((ext_vector_type(2)));
typedef float  f32x4  __attribute__((ext_vector_type(4)));

// x-load pipeline macros: 3-buffer rotation, prefetch distance 2.
// (r4 lesson: use underscore-suffixed names so ## pastes identifier+identifier.)
#define GLOAD(P, ks)                                    \
    P##_0 = *(const float4*)(xp0 + (ks) * 32);          \
    P##_1 = *(const float4*)(xp0 + (ks) * 32 + 4);      \
    P##_2 = *(const float4*)(xp1 + (ks) * 32);          \
    P##_3 = *(const float4*)(xp1 + (ks) * 32 + 4);

#define KSTEP(P, ks) {                                                             \
    bf16x8 af0 = { (__bf16)P##_0.x, (__bf16)P##_0.y, (__bf16)P##_0.z, (__bf16)P##_0.w, \
                   (__bf16)P##_1.x, (__bf16)P##_1.y, (__bf16)P##_1.z, (__bf16)P##_1.w };\
    bf16x8 af1 = { (__bf16)P##_2.x, (__bf16)P##_2.y, (__bf16)P##_2.z, (__bf16)P##_2.w, \
                   (__bf16)P##_3.x, (__bf16)P##_3.y, (__bf16)P##_3.z, (__bf16)P##_3.w };\
    _Pragma("unroll")                                                              \
    for (int nt = 0; nt < 8; nt++) {                                               \
        int nrow = nt * 16 + m;                                                    \
        const bf16x8 bf = *(const bf16x8*)(smem + (nrow << 9) +                    \
                            (((ks) * 64 + quad * 16) ^ ((nrow & 7) << 4)));        \
        acc0[nt] = __builtin_amdgcn_mfma_f32_16x16x32_bf16(af0, bf, acc0[nt], 0, 0, 0); \
        acc1[nt] = __builtin_amdgcn_mfma_f32_16x16x32_bf16(af1, bf, acc1[nt], 0, 0, 0); \
    } }

// ---------------------------------------------------------------------------
// Kernel 1 (fused): blocks [0,196) = GEMM  support = bf16(x @ W);
//                   blocks [196,452) = scatter to fixed-capacity buckets.
// r12: prep kernel deleted. GEMM blocks convert W in-kernel: thread t owns
// col n=t&127, reads w[k][n] (dword loads, 256B-coalesced across lanes),
// writes bf16x4-packed ds_write_b64 into the XOR-swizzled layout
//   LDS byte (n<<9) + (2k ^ ((n&7)<<4)) = bf16(w[k][n])
// (~4-way bank spread; r1 A/B showed in-kernel convert ~= staged copy).
// cursor[] is zeroed by a 3KB hipMemsetAsync (graph-safe, r0 precedent).
// Scatter: bucket g owns slots [g*CAP, g*CAP+CAP) — no exclusive scan
// anywhere; 1 global atomicAdd per (block,bucket) reserves a slice; per-edge
// LDS-atomic ranks. Latency hides under the co-scheduled GEMM blocks.
// NOTE (r9): hipLaunchCooperativeKernel is NOT graph-capturable here.
// ---------------------------------------------------------------------------
__global__ __launch_bounds__(512, 3) void gcn_gemm_scatter(const float* __restrict__ x,
                                                           const float* __restrict__ w,
                                                           __bf16* __restrict__ support,
                                                           const int* __restrict__ erows,
                                                           const int* __restrict__ ecols,
                                                           const float* __restrict__ evals,
                                                           int* __restrict__ cursor,
                                                           int2* __restrict__ bucketed) {
    __shared__ char smem[65536];   // GEMM: W^T then C-tile; scatter: lh[784]
    const int t = threadIdx.x;

    if (blockIdx.x >= GEMM_BLOCKS) {
        // ---------------- scatter part ----------------
        int b = blockIdx.x - GEMM_BLOCKS;         // 0..255
        int* lh = (int*)smem;                     // [NBUCKA] counts -> bases
        for (int j = t; j < NBUCKA; j += 512) lh[j] = 0;
        __syncthreads();
        int e0 = b * EPB;
        int e1 = e0 + EPB; if (e1 > N_EDGES) e1 = N_EDGES;
        int myr[ITERS];
#pragma unroll
        for (int j = 0; j < ITERS; j++) {         // static idx via unroll (rule #20)
            int e = e0 + j * 512 + t;
            myr[j] = -1;
            if (e < e1) {
                int r = erows[e];
                myr[j] = r;
                atomicAdd(&lh[r >> 6], 1);        // LDS atomic
            }
        }
        __syncthreads();
        for (int j0 = t; j0 < NBUCKA; j0 += 512) {  // reserve contiguous slices
            int c = lh[j0];
            lh[j0] = c ? atomicAdd(&cursor[j0], c) : 0;   // global atomic, 1/bucket
        }
        __syncthreads();
#pragma unroll
        for (int j = 0; j < ITERS; j++) {
            int r = myr[j];
            if (r >= 0) {
                int e = e0 + j * 512 + t;
                int g = r >> 6;
                int rank = atomicAdd(&lh[g], 1);  // LDS atomic return
                if (rank < CAP)                   // 9-sigma guard
                    bucketed[((size_t)g << 10) + rank] =
                        make_int2(((r & 63) << 16) | ecols[e],
                                  __float_as_int(evals[e]));
            }
        }
        return;
    }

    // ---------------- GEMM part ----------------
    const int wave = t >> 6;                         // 0..7
    const int lane = t & 63;
    const int m    = lane & 15;
    const int quad = lane >> 4;

    // in-kernel W stage: convert fp32 w -> swizzled bf16 LDS (r12).
    // thread t: col n=t&127, k = 4*(t>>7) + 16j + {0..3}; writes are 8B
    // ds_write_b64 (bf16x4), banks spread by (n&7) XOR -> ~4-way (free-ish).
    {
        int n  = t & 127;
        int kb = (t >> 7) * 4;                       // 0,4,8,12
        int xorv = (n & 7) << 4;
        char* ldsrow = smem + (n << 9);
#pragma unroll 4
        for (int j = 0; j < 16; j++) {
            int k = kb + 16 * j;
            float a0 = w[(k + 0) * OUT_F + n];
            float a1 = w[(k + 1) * OUT_F + n];
            float a2 = w[(k + 2) * OUT_F + n];
            float a3 = w[(k + 3) * OUT_F + n];
            bf16x4 pk = { (__bf16)a0, (__bf16)a1, (__bf16)a2, (__bf16)a3 };
            *(bf16x4*)(ldsrow + ((2 * k) ^ xorv)) = pk;
        }
    }

    const int row0 = blockIdx.x * 256 + wave * 32;
    int r0 = row0 + m;
    int r1 = row0 + 16 + m;
    const float* xp0 = x + (size_t)(r0 < N_NODES ? r0 : 0) * IN_F + quad * 8;
    const float* xp1 = x + (size_t)(r1 < N_NODES ? r1 : 0) * IN_F + quad * 8;

    f32x4 acc0[8], acc1[8];
#pragma unroll
    for (int nt = 0; nt < 8; nt++) {
        acc0[nt] = (f32x4){0.f, 0.f, 0.f, 0.f};
        acc1[nt] = (f32x4){0.f, 0.f, 0.f, 0.f};
    }

    __syncthreads();   // W tile complete in LDS

    float4 A_0, A_1, A_2, A_3, B_0, B_1, B_2, B_3, C_0, C_1, C_2, C_3;
    GLOAD(A, 0) GLOAD(B, 1)
    GLOAD(C, 2) KSTEP(A, 0)
    GLOAD(A, 3) KSTEP(B, 1)
    GLOAD(B, 4) KSTEP(C, 2)
    GLOAD(C, 5) KSTEP(A, 3)
    GLOAD(A, 6) KSTEP(B, 4)
    GLOAD(B, 7) KSTEP(C, 5)
    KSTEP(A, 6)
    KSTEP(B, 7)

    // ---- epilogue: transpose through LDS, then full-line vector stores ----
    __syncthreads();   // all waves done reading W from smem
#pragma unroll
    for (int nt = 0; nt < 8; nt++) {
        int cb = (nt * 16 + m) * 2;                  // col byte offset
#pragma unroll
        for (int r = 0; r < 4; r++) {
            int lr0 = wave * 32 + quad * 4 + r;      // C/D layout [m89]: row=quad*4+r
            int lr1 = lr0 + 16;
            *(__bf16*)(smem + (lr0 << 8) + (cb ^ ((lr0 & 7) << 4))) = (__bf16)acc0[nt][r];
            *(__bf16*)(smem + (lr1 << 8) + (cb ^ ((lr1 & 7) << 4))) = (__bf16)acc1[nt][r];
        }
    }
    __syncthreads();
    {
        int row  = t >> 1;                           // 0..255
        int half = t & 1;
        int g = blockIdx.x * 256 + row;
        if (g < N_NODES) {
            char* dst = (char*)(support + (size_t)g * OUT_F) + half * 128;
#pragma unroll
            for (int j = 0; j < 8; j++) {
                int boff = (half * 128 + j * 16) ^ ((row & 7) << 4);
                *(bf16x8*)(dst + j * 16) = *(const bf16x8*)(smem + (row << 8) + boff);
            }
        }
    }
}

// ---------------------------------------------------------------------------
// Kernel 2 (fused rank+aggregate): one block per 64-row bucket (782 blocks,
// r10 fix for grid-limited occupancy). LDS ~19KB.
//  (a) load slice -> se_raw + histogram(64 bins) -> scan -> LDS rank scatter
//      into se (row-sorted, col|val);
//  (b) aggregate: wave wv owns 8 rows; per row all 64 lanes gather
//      support[col] (256B coalesced), unroll-8 MLP, rows independent.
// ---------------------------------------------------------------------------
__global__ __launch_bounds__(512, 8) void gcn_agg_sorted(const __bf16* __restrict__ support,
                                                         const int2* __restrict__ bucketed,
                                                         const int* __restrict__ cursor,
                                                         const float* __restrict__ bias,
                                                         float* __restrict__ out) {
    __shared__ int2 se_raw[CAP];      // 8 KB unsorted edges (one global pass)
    __shared__ int2 se[CAP];          // 8 KB row-sorted edges (col, val)
    __shared__ int  lh[BROWS];        // per-row counts
    __shared__ int  rs[BROWS];        // per-row exclusive start
    __shared__ int  run[BROWS];       // running cursor for rank scatter
    __shared__ int  sc[128];          // scan buffer
    const int g  = blockIdx.x;
    const int t  = threadIdx.x;
    const int wv = t >> 6, ln = t & 63;

    const int beg = g << 10;                      // g * CAP
    int ne = cursor[g]; if (ne > CAP) ne = CAP; if (ne < 0) ne = 0;

    if (t < BROWS) lh[t] = 0;
    __syncthreads();
    for (int i = t; i < ne; i += 512) {           // single global pass
        int2 cv = bucketed[beg + i];
        se_raw[i] = cv;
        atomicAdd(&lh[cv.x >> 16], 1);
    }
    __syncthreads();

    if (t < 128) {
        int v = (t < BROWS) ? lh[t] : 0;
        sc[t] = v;
    }
    __syncthreads();
#pragma unroll
    for (int off = 1; off < BROWS; off <<= 1) {
        int x = 0;
        if (t < 128 && t >= off) x = sc[t - off];
        __syncthreads();
        if (t < 128) sc[t] += x;
        __syncthreads();
    }
    if (t < BROWS) {
        int v = lh[t];
        rs[t] = sc[t] - v;
        run[t] = sc[t] - v;
    }
    __syncthreads();

    for (int i = t; i < ne; i += 512) {           // LDS -> LDS rank scatter
        int2 cv = se_raw[i];
        int p = atomicAdd(&run[cv.x >> 16], 1);   // p < ne <= CAP by construction
        se[p] = make_int2(cv.x & 0xFFFF, cv.y);
    }
    __syncthreads();

    // aggregate: wave wv owns rows [wv*8, wv*8+8)
    const int grow0 = g * BROWS;
    const __bf16* spL = support + ln * 2;
    const float2 bias2 = *(const float2*)&bias[ln * 2];
    for (int rr = 0; rr < 8; rr++) {
        int row  = wv * 8 + rr;
        int grow = grow0 + row;
        if (grow >= N_NODES) break;               // wave-uniform
        float2 acc = bias2;
        float2 accB = make_float2(0.f, 0.f);
        int b0 = rs[row];
        int b1 = b0 + lh[row];
        int j = b0;
        for (; j + 7 < b1; j += 8) {              // unroll-8: 8 gathers in flight
            int2 e0 = se[j];
            int2 e1 = se[j + 1];
            int2 e2 = se[j + 2];
            int2 e3 = se[j + 3];
            int2 e4 = se[j + 4];
            int2 e5 = se[j + 5];
            int2 e6 = se[j + 6];
            int2 e7 = se[j + 7];
            bf16x2 s0 = *(const bf16x2*)(spL + (size_t)e0.x * OUT_F);
            bf16x2 s1 = *(const bf16x2*)(spL + (size_t)e1.x * OUT_F);
            bf16x2 s2 = *(const bf16x2*)(spL + (size_t)e2.x * OUT_F);
            bf16x2 s3 = *(const bf16x2*)(spL + (size_t)e3.x * OUT_F);
            bf16x2 s4 = *(const bf16x2*)(spL + (size_t)e4.x * OUT_F);
            bf16x2 s5 = *(const bf16x2*)(spL + (size_t)e5.x * OUT_F);
            bf16x2 s6 = *(const bf16x2*)(spL + (size_t)e6.x * OUT_F);
            bf16x2 s7 = *(const bf16x2*)(spL + (size_t)e7.x * OUT_F);
            float v0 = __int_as_float(e0.y);
            float v1 = __int_as_float(e1.y);
            float v2 = __int_as_float(e2.y);
            float v3 = __int_as_float(e3.y);
            float v4 = __int_as_float(e4.y);
            float v5 = __int_as_float(e5.y);
            float v6 = __int_as_float(e6.y);
            float v7 = __int_as_float(e7.y);
            acc.x  += v0 * (float)s0.x + v1 * (float)s1.x;
            acc.y  += v0 * (float)s0.y + v1 * (float)s1.y;
            accB.x += v2 * (float)s2.x + v3 * (float)s3.x;
            accB.y += v2 * (float)s2.y + v3 * (float)s3.y;
            acc.x  += v4 * (float)s4.x + v5 * (float)s5.x;
            acc.y  += v4 * (float)s4.y + v5 * (float)s5.y;
            accB.x += v6 * (float)s6.x + v7 * (float)s7.x;
            accB.y += v6 * (float)s6.y + v7 * (float)s7.y;
        }
        for (; j + 3 < b1; j += 4) {
            int2 e0 = se[j];
            int2 e1 = se[j + 1];
            int2 e2 = se[j + 2];
            int2 e3 = se[j + 3];
            bf16x2 s0 = *(const bf16x2*)(spL + (size_t)e0.x * OUT_F);
            bf16x2 s1 = *(const bf16x2*)(spL + (size_t)e1.x * OUT_F);
            bf16x2 s2 = *(const bf16x2*)(spL + (size_t)e2.x * OUT_F);
            bf16x2 s3 = *(const bf16x2*)(spL + (size_t)e3.x * OUT_F);
            float v0 = __int_as_float(e0.y);
            float v1 = __int_as_float(e1.y);
            float v2 = __int_as_float(e2.y);
            float v3 = __int_as_float(e3.y);
            acc.x  += v0 * (float)s0.x + v1 * (float)s1.x;
            acc.y  += v0 * (float)s0.y + v1 * (float)s1.y;
            accB.x += v2 * (float)s2.x + v3 * (float)s3.x;
            accB.y += v2 * (float)s2.y + v3 * (float)s3.y;
        }
        for (; j < b1; j++) {
            int2 e0 = se[j];
            bf16x2 s0 = *(const bf16x2*)(spL + (size_t)e0.x * OUT_F);
            float v0 = __int_as_float(e0.y);
            acc.x += v0 * (float)s0.x;
            acc.y += v0 * (float)s0.y;
        }
        acc.x += accB.x;
        acc.y += accB.y;
        *(float2*)&out[(size_t)grow * OUT_F + ln * 2] = acc;
    }
}

// ---------------------------------------------------------------------------
static inline size_t align_up(size_t v, size_t a) { return (v + a - 1) & ~(a - 1); }

extern "C" void kernel_launch(void* const* d_in, const int* in_sizes, int n_in,
                              void* d_out, int out_size, void* d_ws, size_t ws_size,
                              hipStream_t stream) {
    const float* x     = (const float*)d_in[0];   // [50000, 256]
    const int*   erows = (const int*)d_in[1];     // [600000]
    const int*   ecols = (const int*)d_in[2];     // [600000]
    const float* evals = (const float*)d_in[3];   // [600000]
    const float* w     = (const float*)d_in[4];   // [256, 128]
    const float* bias  = (const float*)d_in[5];   // [128]
    float* out = (float*)d_out;                   // [50000, 128]

    // workspace layout (all regions 64B-aligned; ~19.5 MB total)
    size_t off = 0;
    __bf16* support   = (__bf16*)((char*)d_ws + off);
    off = align_up(off + (size_t)N_NODES * OUT_F * 2, 64);
    int*    cursor    = (int*)((char*)d_ws + off);        // [784]
    off = align_up(off + (size_t)NBUCKA * 4, 64);
    int2*   bucketed  = (int2*)((char*)d_ws + off);       // [782][1024]

    // 0) zero bucket cursors (3 KB, stream-ordered, graph-capturable)
    hipMemsetAsync(cursor, 0, (size_t)NBUCKA * sizeof(int), stream);

    // 1) fused GEMM (in-kernel W convert) + fixed-capacity bucket scatter
    gcn_gemm_scatter<<<GEMM_BLOCKS + NBLK_E, 512, 0, stream>>>(
        x, w, support, erows, ecols, evals, cursor, bucketed);

    // 2) fused in-LDS rank + per-row-wave aggregate + bias
    gcn_agg_sorted<<<NBUCK, 512, 0, stream>>>(support, bucketed, cursor, bias, out);
}